// Round 9
// baseline (510.602 us; speedup 1.0000x reference)
//
#include <hip/hip_runtime.h>
#include <math.h>

namespace {

constexpr int   B_ = 2;
constexpr int   N_ = 16384;
constexpr int   M_ = 2048;
constexpr int   D_ = 256;
constexpr float SCALE_  = 0.0625f;   // 1/sqrt(256)
constexpr float LN_EPS_ = 1e-5f;
constexpr int   NS_  = 16;           // n-splits in attn_out (R8: revert to 16)
constexpr int   NPB_ = N_ / NS_;     // 1024 n per block
constexpr int   NCOPY_ = 8;          // XCD-private out partials
constexpr size_t OUTSZ_ = (size_t)B_*M_*D_;

typedef _Float16 f16x8 __attribute__((ext_vector_type(8)));
typedef float    f32x16 __attribute__((ext_vector_type(16)));

__device__ inline f16x8 as_h8(uint4 u) { return __builtin_bit_cast(f16x8, u); }
__device__ inline unsigned short f16bits(float x) {
    return __builtin_bit_cast(unsigned short, (_Float16)x);
}
__device__ inline uint4 pack8(const unsigned short v[8]) {
    return make_uint4((uint32_t)v[0] | ((uint32_t)v[1] << 16),
                      (uint32_t)v[2] | ((uint32_t)v[3] << 16),
                      (uint32_t)v[4] | ((uint32_t)v[5] << 16),
                      (uint32_t)v[6] | ((uint32_t)v[7] << 16));
}
#define MFMA16(acc, a, b) (acc) = __builtin_amdgcn_mfma_f32_32x32x16_f16((a), (b), (acc), 0, 0, 0)

// C/D layout for 32x32 MFMA: col = lane&31, row = (reg&3)+8*(reg>>2)+4*(lane>>5)
__device__ inline int cd_row(int reg, int lane) {
    return (reg & 3) + 8 * (reg >> 2) + 4 * (lane >> 5);
}

// Packet layout (fp16 single-plane operands):
//   A/B-fragment packet p = tile32*16 + ks ; element = packet*64 + lane (uint4 = 8 fp16)
//   lane holds  X[tile32*32 + (lane&31)][ks*16 + (lane>>5)*8 + j]  j=0..7
// V packets: packet = gg*8 + dt (gg = flat_n/16, dt = d/32); lane holds
//   V[gg*16 + (lane>>5)*8 + j][dt*32 + (lane&31)]

// ---------------- P0: W -> B-operand packets (single fp16 plane) ----------------
__global__ void prep_wt(const float* __restrict__ Wq, const float* __restrict__ Wk,
                        const float* __restrict__ Wv, uint4* __restrict__ wp) {
    __shared__ unsigned short ldb[256 * 33];
    const int mat = blockIdx.x >> 3;
    const int Tc  = blockIdx.x & 7;
    const float* W = (mat == 0) ? Wq : (mat == 1) ? Wk : Wv;
    const int d = threadIdx.x;
    #pragma unroll
    for (int c = 0; c < 32; c += 4) {
        const float4 v = *reinterpret_cast<const float4*>(&W[d * D_ + Tc * 32 + c]);
        ldb[d * 33 + c + 0] = f16bits(v.x);
        ldb[d * 33 + c + 1] = f16bits(v.y);
        ldb[d * 33 + c + 2] = f16bits(v.z);
        ldb[d * 33 + c + 3] = f16bits(v.w);
    }
    __syncthreads();
    const int lane = threadIdx.x & 63;
    const int pg   = threadIdx.x >> 6;
    #pragma unroll
    for (int kq = 0; kq < 4; ++kq) {
        const int ks = pg * 4 + kq;
        unsigned short hh[8];
        #pragma unroll
        for (int j = 0; j < 8; ++j)
            hh[j] = ldb[(ks * 16 + (lane >> 5) * 8 + j) * 33 + (lane & 31)];
        wp[((size_t)((mat * 8 + Tc) * 16 + ks)) * 64 + lane] = pack8(hh);
    }
}

// ---------------- P1: hr = relu(LN(|p-v| @ Wp1 + bp1)) ----------------
__global__ void prep_hr(const float* __restrict__ p_xyz, const float* __restrict__ v_xyz,
                        const float* __restrict__ Wp1, const float* __restrict__ bp1,
                        const float* __restrict__ ln_w, const float* __restrict__ ln_b,
                        float4* __restrict__ hr4) {
    const int r = blockIdx.x * 256 + threadIdx.x;
    if (r >= B_ * N_) return;
    const int b = r / N_;
    const float d0 = fabsf(p_xyz[r*3+0] - v_xyz[b*3+0]);
    const float d1 = fabsf(p_xyz[r*3+1] - v_xyz[b*3+1]);
    const float d2 = fabsf(p_xyz[r*3+2] - v_xyz[b*3+2]);
    float h[3];
    #pragma unroll
    for (int j = 0; j < 3; ++j)
        h[j] = d0*Wp1[0*3+j] + d1*Wp1[1*3+j] + d2*Wp1[2*3+j] + bp1[j];
    const float mu = (h[0]+h[1]+h[2]) * (1.0f/3.0f);
    const float e0 = h[0]-mu, e1 = h[1]-mu, e2 = h[2]-mu;
    const float var = (e0*e0 + e1*e1 + e2*e2) * (1.0f/3.0f);
    const float inv = rsqrtf(var + LN_EPS_);
    hr4[r] = make_float4(fmaxf(e0*inv*ln_w[0] + ln_b[0], 0.0f),
                         fmaxf(e1*inv*ln_w[1] + ln_b[1], 0.0f),
                         fmaxf(e2*inv*ln_w[2] + ln_b[2], 0.0f), 0.0f);
}

// ---------------- K1: projection GEMM -> fp16 packet outputs ----------------
template<int MODE>
__global__ void gemm_qkv(const float* __restrict__ in,
                         const uint4* __restrict__ wp,
                         const float* __restrict__ bias,
                         const float4* __restrict__ hr4,
                         const float* __restrict__ Wp2, const float* __restrict__ bp2,
                         uint4* __restrict__ op) {
    __shared__ unsigned short tb[4][32 * 33];
    const int tid  = threadIdx.x;
    const int lane = tid & 63;
    const int w    = tid >> 6;
    const int wr   = w & 1;
    const int wc   = w >> 1;
    const int lane31 = lane & 31;
    const int Trow = blockIdx.x * 2 + wr;                 // 32-row tile index (flat)
    const int rowA = Trow * 32 + lane31;
    const float* ap = in + (size_t)rowA * D_ + (lane >> 5) * 8;

    f32x16 acc[4];
    #pragma unroll
    for (int t = 0; t < 4; ++t) acc[t] = (f32x16)0.0f;

    union U8 { _Float16 f[8]; f16x8 v; };
    #pragma unroll 4
    for (int ks = 0; ks < 16; ++ks) {
        const float4 f0 = *reinterpret_cast<const float4*>(ap + ks*16);
        const float4 f1 = *reinterpret_cast<const float4*>(ap + ks*16 + 4);
        const float xs[8] = {f0.x, f0.y, f0.z, f0.w, f1.x, f1.y, f1.z, f1.w};
        U8 ah, al;
        #pragma unroll
        for (int j = 0; j < 8; ++j) {
            ah.f[j] = (_Float16)xs[j];
            al.f[j] = (_Float16)(xs[j] - (float)ah.f[j]);
        }
        #pragma unroll
        for (int t = 0; t < 4; ++t) {
            const f16x8 bh = as_h8(wp[((size_t)((wc * 4 + t) * 16 + ks)) * 64 + lane]);
            MFMA16(acc[t], ah.v, bh);
            MFMA16(acc[t], al.v, bh);
        }
    }

    float biasc[4], w0c[4], w1c[4], w2c[4], b2c[4];
    #pragma unroll
    for (int t = 0; t < 4; ++t) {
        const int cc = wc * 128 + t * 32 + lane31;
        biasc[t] = bias[cc];
        if (MODE == 1) {
            w0c[t] = Wp2[0*D_ + cc]; w1c[t] = Wp2[1*D_ + cc];
            w2c[t] = Wp2[2*D_ + cc]; b2c[t] = bp2[cc];
        }
    }
    float4 hv[16];
    if (MODE == 1) {
        #pragma unroll
        for (int r = 0; r < 16; ++r) hv[r] = hr4[Trow * 32 + cd_row(r, lane)];
    }

    #pragma unroll
    for (int t = 0; t < 4; ++t) {
        #pragma unroll
        for (int r = 0; r < 16; ++r) {
            float v = acc[t][r] + biasc[t];
            if (MODE == 1) v += hv[r].x*w0c[t] + hv[r].y*w1c[t] + hv[r].z*w2c[t] + b2c[t];
            tb[w][cd_row(r, lane) * 33 + lane31] = f16bits(v);
        }
        if (MODE != 2) {
            #pragma unroll
            for (int p = 0; p < 2; ++p) {
                unsigned short hh[8];
                #pragma unroll
                for (int j = 0; j < 8; ++j)
                    hh[j] = tb[w][lane31 * 33 + p * 16 + (lane >> 5) * 8 + j];
                op[((size_t)(Trow * 16 + wc * 8 + t * 2 + p)) * 64 + lane] = pack8(hh);
            }
        } else {
            #pragma unroll
            for (int h16 = 0; h16 < 2; ++h16) {
                unsigned short hh[8];
                #pragma unroll
                for (int j = 0; j < 8; ++j)
                    hh[j] = tb[w][(h16 * 16 + (lane >> 5) * 8 + j) * 33 + lane31];
                op[((size_t)((Trow * 2 + h16) * 8 + wc * 4 + t)) * 64 + lane] = pack8(hh);
            }
        }
    }
}

// ---------------- K2: per-(b,n) softmax stats over m ----------------
__device__ inline void load_q16(uint4 dst[16], const uint4* __restrict__ qp, size_t base) {
    #pragma unroll
    for (int ks = 0; ks < 16; ++ks) dst[ks] = qp[base + (size_t)ks * 64];
}
__device__ inline void mfma_tile(f32x16& s0, f32x16& s1, const uint4 q[16], const uint4 kf[16]) {
    #pragma unroll
    for (int ks = 0; ks < 16; ks += 2) {
        MFMA16(s0, as_h8(q[ks]),   as_h8(kf[ks]));
        MFMA16(s1, as_h8(q[ks+1]), as_h8(kf[ks+1]));
    }
}
__device__ inline void upd_stats(const f32x16& s0, const f32x16& s1, float& cm, float& cs) {
    float sm[16], tmax = -INFINITY;
    #pragma unroll
    for (int r = 0; r < 16; ++r) { sm[r] = (s0[r] + s1[r]) * SCALE_; tmax = fmaxf(tmax, sm[r]); }
    const float nm = fmaxf(cm, tmax);
    const float f  = __expf(cm - nm);
    float ts = 0.0f;
    #pragma unroll
    for (int r = 0; r < 16; ++r) ts += __expf(sm[r] - nm);
    cs = cs * f + ts;
    cm = nm;
}

__global__ __launch_bounds__(256, 1)
void col_stats(const uint4* __restrict__ qp, const uint4* __restrict__ kp,
               float* __restrict__ cmax, float* __restrict__ cinv) {
    __shared__ float mbuf[2][32], sbuf[2][32];
    const int tid  = threadIdx.x;
    const int lane = tid & 63;
    const int w    = tid >> 6;
    const int wn   = w & 1;
    const int wm   = w >> 1;
    const int bid  = blockIdx.x;
    const int x8   = bid & 7;
    const int b    = x8 >> 2;                        // XCD batch pinning
    const int loc  = (bid >> 3) * 4 + (x8 & 3);      // 0..255
    const int n0   = loc * 64 + wn * 32;             // within-batch n base (this wave)
    const int Tk   = (b * N_ + n0) >> 5;

    uint4 kf[16];
    #pragma unroll
    for (int ks = 0; ks < 16; ++ks)
        kf[ks] = kp[((size_t)(Tk * 16 + ks)) * 64 + lane];

    const size_t qbase = ((size_t)(b * (M_ / 32)) * 16) * 64 + lane;
    const size_t qstep = 16 * 64;                    // packets per m-tile
    uint4 qA[16], qB[16];
    load_q16(qA, qp, qbase + (size_t)wm * qstep);    // tiles: wm, wm+2, ..., 62

    float cm = -INFINITY, cs = 0.0f;
    const f32x16 z = (f32x16)0.0f;
    for (int m4 = 0; m4 < 16; ++m4) {
        const int t1 = wm + 4 * m4 + 2;
        load_q16(qB, qp, qbase + (size_t)t1 * qstep);
        f32x16 sa0 = z, sa1 = z;
        mfma_tile(sa0, sa1, qA, kf);
        upd_stats(sa0, sa1, cm, cs);
        if (m4 < 15) load_q16(qA, qp, qbase + (size_t)(t1 + 2) * qstep);
        f32x16 sb0 = z, sb1 = z;
        mfma_tile(sb0, sb1, qB, kf);
        upd_stats(sb0, sb1, cm, cs);
    }
    const float ocm = __shfl_xor(cm, 32, 64);
    const float ocs = __shfl_xor(cs, 32, 64);
    const float nm1 = fmaxf(cm, ocm);
    const float tt1 = cs * __expf(cm - nm1) + ocs * __expf(ocm - nm1);
    if (wm == 1 && lane < 32) { mbuf[wn][lane] = nm1; sbuf[wn][lane] = tt1; }
    __syncthreads();
    if (wm == 0 && lane < 32) {
        const float m2 = mbuf[wn][lane], s2 = sbuf[wn][lane];
        const float mm = fmaxf(nm1, m2);
        const float tt = tt1 * __expf(nm1 - mm) + s2 * __expf(m2 - mm);
        cmax[b * N_ + n0 + lane] = mm;
        cinv[b * N_ + n0 + lane] = 1.0f / tt;
    }
}

// ---------------- K4: part[g&7] += softmax-weighted V ----------------
// 512 threads / 8 waves; m-tile 128. Wave (wm = w&3, wd = w>>2):
//   phase A: S quadrant rows wm*32, n-cols wd*32 (one f32x16 acc)
//   phase B: rows wm*32, d-range wd*128 (oacc[4] = 64 AGPR)
// Per-wave regs ~64 AGPR + ~60 arch -> 4 waves/SIMD (vs R6/R7's 2).
// Swizzle: bid = low3 + 8*(mt*4 + ghi); g = ghi*8+low3; all 16 m-tiles of g
// share bid%8 (XCD) -> K/V L2 locality + XCD-local part atomics.
__global__ __launch_bounds__(512, 4)
void attn_out(const uint4* __restrict__ qp, const uint4* __restrict__ kp,
              const uint4* __restrict__ vp,
              const float* __restrict__ cmax, const float* __restrict__ cinv,
              float* __restrict__ part) {
    __shared__ unsigned short Ph[128 * 72];
    const int tid  = threadIdx.x;
    const int lane = tid & 63;
    const int w    = tid >> 6;        // 0..7
    const int wm   = w & 3;           // m-subtile (32 rows)
    const int wd   = w >> 2;          // n-half (A) / d-half (B)
    const int lane31 = lane & 31;
    const int kh8    = (lane >> 5) * 8;

    const int bid  = blockIdx.x;
    const int low3 = bid & 7;
    const int rest = bid >> 3;
    const int ghi  = rest & 3;
    const int mt   = rest >> 2;       // 0..15
    const int g    = ghi * 8 + low3;  // 0..31
    const int b    = g >> 4;
    const int ns   = g & 15;
    const int m0   = mt * 128;

    const size_t qb = ((size_t)(((b * M_ + m0) >> 5) + wm) * 16) * 64 + lane;

    f32x16 oacc[4];
    #pragma unroll
    for (int t = 0; t < 4; ++t) oacc[t] = (f32x16)0.0f;

    for (int c = 0; c < NPB_ / 64; ++c) {
        const int nbase = ns * NPB_ + c * 64;
        // ---- phase A: S quadrant (rows wm*32, n-cols wd*32) ----
        const size_t kb = ((size_t)(((b * N_ + nbase) >> 5) + wd) * 16) * 64 + lane;
        f32x16 s = (f32x16)0.0f;
        #pragma unroll
        for (int ks = 0; ks < 16; ++ks)
            MFMA16(s, as_h8(qp[qb + ks * 64]), as_h8(kp[kb + ks * 64]));
        const int nc = nbase + wd * 32 + lane31;
        const float cmv = cmax[b * N_ + nc];
        const float civ = cinv[b * N_ + nc];
        #pragma unroll
        for (int r = 0; r < 16; ++r) {
            const int row = wm * 32 + cd_row(r, lane);
            Ph[row * 72 + wd * 32 + lane31] = f16bits(__expf(s[r] * SCALE_ - cmv) * civ);
        }
        __syncthreads();
        // ---- phase B: oacc(32 m x 128 d) += P @ V ----
        const unsigned short* prh = Ph + (wm * 32 + lane31) * 72 + kh8;
        const size_t gg0 = (size_t)((b * N_ + nbase) >> 4);
        #pragma unroll
        for (int k2 = 0; k2 < 4; ++k2) {
            const f16x8 a2 = as_h8(*reinterpret_cast<const uint4*>(prh + k2 * 16));
            #pragma unroll
            for (int dt = 0; dt < 4; ++dt) {
                MFMA16(oacc[dt], a2, as_h8(vp[((gg0 + k2) * 8 + wd * 4 + dt) * 64 + lane]));
            }
        }
        __syncthreads();
    }
    float* pb = part + (size_t)low3 * OUTSZ_;
    #pragma unroll
    for (int dt = 0; dt < 4; ++dt) {
        #pragma unroll
        for (int r = 0; r < 16; ++r) {
            const int row  = m0 + wm * 32 + cd_row(r, lane);
            atomicAdd(&pb[((size_t)(b * M_ + row)) * D_ + wd * 128 + dt * 32 + lane31],
                      oacc[dt][r]);
        }
    }
}

// ---------------- K5: out = v_features + sum(parts) ----------------
__global__ void reduce_out(const float4* __restrict__ v, const float4* __restrict__ part,
                           float4* __restrict__ out) {
    const size_t i = (size_t)blockIdx.x * 256 + threadIdx.x;
    float4 a = v[i];
    #pragma unroll
    for (int c = 0; c < NCOPY_; ++c) {
        const float4 p = part[(size_t)c * (OUTSZ_ / 4) + i];
        a.x += p.x; a.y += p.y; a.z += p.z; a.w += p.w;
    }
    out[i] = a;
}

} // anonymous namespace

extern "C" void kernel_launch(void* const* d_in, const int* in_sizes, int n_in,
                              void* d_out, int out_size, void* d_ws, size_t ws_size,
                              hipStream_t stream) {
    const float* p_xyz      = (const float*)d_in[0];
    const float* v_xyz      = (const float*)d_in[1];
    const float* p_features = (const float*)d_in[2];
    const float* v_features = (const float*)d_in[3];
    const float* Wq  = (const float*)d_in[4];
    const float* bq  = (const float*)d_in[5];
    const float* Wk  = (const float*)d_in[6];
    const float* bk  = (const float*)d_in[7];
    const float* Wv  = (const float*)d_in[8];
    const float* bv  = (const float*)d_in[9];
    const float* Wp1 = (const float*)d_in[10];
    const float* bp1 = (const float*)d_in[11];
    const float* lnw = (const float*)d_in[12];
    const float* lnb = (const float*)d_in[13];
    const float* Wp2 = (const float*)d_in[14];
    const float* bp2 = (const float*)d_in[15];
    float* out = (float*)d_out;

    // ---- workspace carve-up (256B aligned), ~70 MB ----
    char* p = (char*)d_ws;
    auto alloc = [&](size_t bytes) {
        void* r = (void*)p;
        p += (bytes + 255) & ~(size_t)255;
        return r;
    };
    uint4* qpk = (uint4*)alloc((size_t)B_*M_*D_*2);   // fp16 packets
    uint4* kpk = (uint4*)alloc((size_t)B_*N_*D_*2);
    uint4* vpk = (uint4*)alloc((size_t)B_*N_*D_*2);
    uint4* wp  = (uint4*)alloc((size_t)3*D_*D_*2);
    float4* hr4 = (float4*)alloc((size_t)B_*N_*16);
    float*  cm  = (float*)alloc((size_t)B_*N_*4);
    float*  ci  = (float*)alloc((size_t)B_*N_*4);
    float*  part = (float*)alloc((size_t)NCOPY_*OUTSZ_*4);   // 33.5 MB

    constexpr size_t WMAT = (size_t)D_*D_/8;   // uint4 per weight matrix

    prep_wt<<<3*8, 256, 0, stream>>>(Wq, Wk, Wv, wp);
    prep_hr<<<(B_*N_)/256, 256, 0, stream>>>(p_xyz, v_xyz, Wp1, bp1, lnw, lnb, hr4);
    hipMemsetAsync(part, 0, (size_t)NCOPY_*OUTSZ_*4, stream);

    gemm_qkv<0><<<(B_*M_)/64, 256, 0, stream>>>(v_features, wp + 0*WMAT, bq, hr4, Wp2, bp2, qpk);
    gemm_qkv<1><<<(B_*N_)/64, 256, 0, stream>>>(p_features, wp + 1*WMAT, bk, hr4, Wp2, bp2, kpk);
    gemm_qkv<2><<<(B_*N_)/64, 256, 0, stream>>>(p_features, wp + 2*WMAT, bv, hr4, Wp2, bp2, vpk);

    col_stats<<<512, 256, 0, stream>>>(qpk, kpk, cm, ci);
    attn_out<<<B_*NS_*(M_/128), 512, 0, stream>>>(qpk, kpk, vpk, cm, ci, part);
    reduce_out<<<(OUTSZ_/4)/256, 256, 0, stream>>>((const float4*)v_features,
                                                   (const float4*)part, (float4*)out);
}

// Round 10
// 413.982 us; speedup vs baseline: 1.2334x; 1.2334x over previous
//
#include <hip/hip_runtime.h>
#include <math.h>

namespace {

constexpr int   B_ = 2;
constexpr int   N_ = 16384;
constexpr int   M_ = 2048;
constexpr int   D_ = 256;
constexpr float SCALE_  = 0.0625f;   // 1/sqrt(256)
constexpr float LN_EPS_ = 1e-5f;
constexpr int   NS_  = 16;           // n-splits in attn_out
constexpr int   NPB_ = N_ / NS_;     // 1024 n per block
constexpr int   NCOPY_ = 8;          // XCD-private out partials
constexpr size_t OUTSZ_ = (size_t)B_*M_*D_;

typedef _Float16 f16x8 __attribute__((ext_vector_type(8)));
typedef float    f32x16 __attribute__((ext_vector_type(16)));

__device__ inline f16x8 as_h8(uint4 u) { return __builtin_bit_cast(f16x8, u); }
__device__ inline unsigned short f16bits(float x) {
    return __builtin_bit_cast(unsigned short, (_Float16)x);
}
__device__ inline uint4 pack8(const unsigned short v[8]) {
    return make_uint4((uint32_t)v[0] | ((uint32_t)v[1] << 16),
                      (uint32_t)v[2] | ((uint32_t)v[3] << 16),
                      (uint32_t)v[4] | ((uint32_t)v[5] << 16),
                      (uint32_t)v[6] | ((uint32_t)v[7] << 16));
}
#define MFMA16(acc, a, b) (acc) = __builtin_amdgcn_mfma_f32_32x32x16_f16((a), (b), (acc), 0, 0, 0)

// C/D layout for 32x32 MFMA: col = lane&31, row = (reg&3)+8*(reg>>2)+4*(lane>>5)
__device__ inline int cd_row(int reg, int lane) {
    return (reg & 3) + 8 * (reg >> 2) + 4 * (lane >> 5);
}

// Packet layout (fp16 single-plane operands):
//   A/B-fragment packet p = tile32*16 + ks ; element = packet*64 + lane (uint4 = 8 fp16)
//   lane holds  X[tile32*32 + (lane&31)][ks*16 + (lane>>5)*8 + j]  j=0..7
// V packets: packet = gg*8 + dt (gg = flat_n/16, dt = d/32); lane holds
//   V[gg*16 + (lane>>5)*8 + j][dt*32 + (lane&31)]

// ---------------- P0: W -> B-operand packets (single fp16 plane) ----------------
__global__ void prep_wt(const float* __restrict__ Wq, const float* __restrict__ Wk,
                        const float* __restrict__ Wv, uint4* __restrict__ wp) {
    __shared__ unsigned short ldb[256 * 33];
    const int mat = blockIdx.x >> 3;
    const int Tc  = blockIdx.x & 7;
    const float* W = (mat == 0) ? Wq : (mat == 1) ? Wk : Wv;
    const int d = threadIdx.x;
    #pragma unroll
    for (int c = 0; c < 32; c += 4) {
        const float4 v = *reinterpret_cast<const float4*>(&W[d * D_ + Tc * 32 + c]);
        ldb[d * 33 + c + 0] = f16bits(v.x);
        ldb[d * 33 + c + 1] = f16bits(v.y);
        ldb[d * 33 + c + 2] = f16bits(v.z);
        ldb[d * 33 + c + 3] = f16bits(v.w);
    }
    __syncthreads();
    const int lane = threadIdx.x & 63;
    const int pg   = threadIdx.x >> 6;
    #pragma unroll
    for (int kq = 0; kq < 4; ++kq) {
        const int ks = pg * 4 + kq;
        unsigned short hh[8];
        #pragma unroll
        for (int j = 0; j < 8; ++j)
            hh[j] = ldb[(ks * 16 + (lane >> 5) * 8 + j) * 33 + (lane & 31)];
        wp[((size_t)((mat * 8 + Tc) * 16 + ks)) * 64 + lane] = pack8(hh);
    }
}

// ---------------- P1: hr = relu(LN(|p-v| @ Wp1 + bp1)) ----------------
__global__ void prep_hr(const float* __restrict__ p_xyz, const float* __restrict__ v_xyz,
                        const float* __restrict__ Wp1, const float* __restrict__ bp1,
                        const float* __restrict__ ln_w, const float* __restrict__ ln_b,
                        float4* __restrict__ hr4) {
    const int r = blockIdx.x * 256 + threadIdx.x;
    if (r >= B_ * N_) return;
    const int b = r / N_;
    const float d0 = fabsf(p_xyz[r*3+0] - v_xyz[b*3+0]);
    const float d1 = fabsf(p_xyz[r*3+1] - v_xyz[b*3+1]);
    const float d2 = fabsf(p_xyz[r*3+2] - v_xyz[b*3+2]);
    float h[3];
    #pragma unroll
    for (int j = 0; j < 3; ++j)
        h[j] = d0*Wp1[0*3+j] + d1*Wp1[1*3+j] + d2*Wp1[2*3+j] + bp1[j];
    const float mu = (h[0]+h[1]+h[2]) * (1.0f/3.0f);
    const float e0 = h[0]-mu, e1 = h[1]-mu, e2 = h[2]-mu;
    const float var = (e0*e0 + e1*e1 + e2*e2) * (1.0f/3.0f);
    const float inv = rsqrtf(var + LN_EPS_);
    hr4[r] = make_float4(fmaxf(e0*inv*ln_w[0] + ln_b[0], 0.0f),
                         fmaxf(e1*inv*ln_w[1] + ln_b[1], 0.0f),
                         fmaxf(e2*inv*ln_w[2] + ln_b[2], 0.0f), 0.0f);
}

// ---------------- K1: projection GEMM -> fp16 packet outputs ----------------
template<int MODE>
__global__ void gemm_qkv(const float* __restrict__ in,
                         const uint4* __restrict__ wp,
                         const float* __restrict__ bias,
                         const float4* __restrict__ hr4,
                         const float* __restrict__ Wp2, const float* __restrict__ bp2,
                         uint4* __restrict__ op) {
    __shared__ unsigned short tb[4][32 * 33];
    const int tid  = threadIdx.x;
    const int lane = tid & 63;
    const int w    = tid >> 6;
    const int wr   = w & 1;
    const int wc   = w >> 1;
    const int lane31 = lane & 31;
    const int Trow = blockIdx.x * 2 + wr;                 // 32-row tile index (flat)
    const int rowA = Trow * 32 + lane31;
    const float* ap = in + (size_t)rowA * D_ + (lane >> 5) * 8;

    f32x16 acc[4];
    #pragma unroll
    for (int t = 0; t < 4; ++t) acc[t] = (f32x16)0.0f;

    union U8 { _Float16 f[8]; f16x8 v; };
    #pragma unroll 4
    for (int ks = 0; ks < 16; ++ks) {
        const float4 f0 = *reinterpret_cast<const float4*>(ap + ks*16);
        const float4 f1 = *reinterpret_cast<const float4*>(ap + ks*16 + 4);
        const float xs[8] = {f0.x, f0.y, f0.z, f0.w, f1.x, f1.y, f1.z, f1.w};
        U8 ah, al;
        #pragma unroll
        for (int j = 0; j < 8; ++j) {
            ah.f[j] = (_Float16)xs[j];
            al.f[j] = (_Float16)(xs[j] - (float)ah.f[j]);
        }
        #pragma unroll
        for (int t = 0; t < 4; ++t) {
            const f16x8 bh = as_h8(wp[((size_t)((wc * 4 + t) * 16 + ks)) * 64 + lane]);
            MFMA16(acc[t], ah.v, bh);
            MFMA16(acc[t], al.v, bh);
        }
    }

    float biasc[4], w0c[4], w1c[4], w2c[4], b2c[4];
    #pragma unroll
    for (int t = 0; t < 4; ++t) {
        const int cc = wc * 128 + t * 32 + lane31;
        biasc[t] = bias[cc];
        if (MODE == 1) {
            w0c[t] = Wp2[0*D_ + cc]; w1c[t] = Wp2[1*D_ + cc];
            w2c[t] = Wp2[2*D_ + cc]; b2c[t] = bp2[cc];
        }
    }
    float4 hv[16];
    if (MODE == 1) {
        #pragma unroll
        for (int r = 0; r < 16; ++r) hv[r] = hr4[Trow * 32 + cd_row(r, lane)];
    }

    #pragma unroll
    for (int t = 0; t < 4; ++t) {
        #pragma unroll
        for (int r = 0; r < 16; ++r) {
            float v = acc[t][r] + biasc[t];
            if (MODE == 1) v += hv[r].x*w0c[t] + hv[r].y*w1c[t] + hv[r].z*w2c[t] + b2c[t];
            tb[w][cd_row(r, lane) * 33 + lane31] = f16bits(v);
        }
        if (MODE != 2) {
            #pragma unroll
            for (int p = 0; p < 2; ++p) {
                unsigned short hh[8];
                #pragma unroll
                for (int j = 0; j < 8; ++j)
                    hh[j] = tb[w][lane31 * 33 + p * 16 + (lane >> 5) * 8 + j];
                op[((size_t)(Trow * 16 + wc * 8 + t * 2 + p)) * 64 + lane] = pack8(hh);
            }
        } else {
            #pragma unroll
            for (int h16 = 0; h16 < 2; ++h16) {
                unsigned short hh[8];
                #pragma unroll
                for (int j = 0; j < 8; ++j)
                    hh[j] = tb[w][(h16 * 16 + (lane >> 5) * 8 + j) * 33 + lane31];
                op[((size_t)((Trow * 2 + h16) * 8 + wc * 4 + t)) * 64 + lane] = pack8(hh);
            }
        }
    }
}

// ---------------- K2: per-(b,n) softmax stats over m ----------------
__device__ inline void load_q16(uint4 dst[16], const uint4* __restrict__ qp, size_t base) {
    #pragma unroll
    for (int ks = 0; ks < 16; ++ks) dst[ks] = qp[base + (size_t)ks * 64];
}
__device__ inline void mfma_tile(f32x16& s0, f32x16& s1, const uint4 q[16], const uint4 kf[16]) {
    #pragma unroll
    for (int ks = 0; ks < 16; ks += 2) {
        MFMA16(s0, as_h8(q[ks]),   as_h8(kf[ks]));
        MFMA16(s1, as_h8(q[ks+1]), as_h8(kf[ks+1]));
    }
}
__device__ inline void upd_stats(const f32x16& s0, const f32x16& s1, float& cm, float& cs) {
    float sm[16], tmax = -INFINITY;
    #pragma unroll
    for (int r = 0; r < 16; ++r) { sm[r] = (s0[r] + s1[r]) * SCALE_; tmax = fmaxf(tmax, sm[r]); }
    const float nm = fmaxf(cm, tmax);
    const float f  = __expf(cm - nm);
    float ts = 0.0f;
    #pragma unroll
    for (int r = 0; r < 16; ++r) ts += __expf(sm[r] - nm);
    cs = cs * f + ts;
    cm = nm;
}

__global__ __launch_bounds__(256, 1)
void col_stats(const uint4* __restrict__ qp, const uint4* __restrict__ kp,
               float* __restrict__ cmax, float* __restrict__ cinv) {
    __shared__ float mbuf[2][32], sbuf[2][32];
    const int tid  = threadIdx.x;
    const int lane = tid & 63;
    const int w    = tid >> 6;
    const int wn   = w & 1;
    const int wm   = w >> 1;
    const int bid  = blockIdx.x;
    const int x8   = bid & 7;
    const int b    = x8 >> 2;                        // XCD batch pinning
    const int loc  = (bid >> 3) * 4 + (x8 & 3);      // 0..255
    const int n0   = loc * 64 + wn * 32;             // within-batch n base (this wave)
    const int Tk   = (b * N_ + n0) >> 5;

    uint4 kf[16];
    #pragma unroll
    for (int ks = 0; ks < 16; ++ks)
        kf[ks] = kp[((size_t)(Tk * 16 + ks)) * 64 + lane];

    const size_t qbase = ((size_t)(b * (M_ / 32)) * 16) * 64 + lane;
    const size_t qstep = 16 * 64;                    // packets per m-tile
    uint4 qA[16], qB[16];
    load_q16(qA, qp, qbase + (size_t)wm * qstep);    // tiles: wm, wm+2, ..., 62

    float cm = -INFINITY, cs = 0.0f;
    const f32x16 z = (f32x16)0.0f;
    for (int m4 = 0; m4 < 16; ++m4) {
        const int t1 = wm + 4 * m4 + 2;
        load_q16(qB, qp, qbase + (size_t)t1 * qstep);
        f32x16 sa0 = z, sa1 = z;
        mfma_tile(sa0, sa1, qA, kf);
        upd_stats(sa0, sa1, cm, cs);
        if (m4 < 15) load_q16(qA, qp, qbase + (size_t)(t1 + 2) * qstep);
        f32x16 sb0 = z, sb1 = z;
        mfma_tile(sb0, sb1, qB, kf);
        upd_stats(sb0, sb1, cm, cs);
    }
    const float ocm = __shfl_xor(cm, 32, 64);
    const float ocs = __shfl_xor(cs, 32, 64);
    const float nm1 = fmaxf(cm, ocm);
    const float tt1 = cs * __expf(cm - nm1) + ocs * __expf(ocm - nm1);
    if (wm == 1 && lane < 32) { mbuf[wn][lane] = nm1; sbuf[wn][lane] = tt1; }
    __syncthreads();
    if (wm == 0 && lane < 32) {
        const float m2 = mbuf[wn][lane], s2 = sbuf[wn][lane];
        const float mm = fmaxf(nm1, m2);
        const float tt = tt1 * __expf(nm1 - mm) + s2 * __expf(m2 - mm);
        cmax[b * N_ + n0 + lane] = mm;
        cinv[b * N_ + n0 + lane] = 1.0f / tt;
    }
}

// ---------------- K4: part[g&7] += softmax-weighted V ----------------
// 512 threads / 8 waves; m-tile 128; NS=16 (512 blocks). Wave (wm=w&3, wd=w>>2).
// q tile held in REGISTERS (16 uint4/wave, loaded once) -> q removed from the
// XCD L2 working set (R8's thrash source); K/V slices alone = 4 MB/XCD = L2.
// Ph double-buffered -> ONE barrier per chunk (chunk c writes Ph[c&1]; a wave
// can be at most 1 chunk ahead, and adjacent chunks use different buffers).
__global__ __launch_bounds__(512, 2)
void attn_out(const uint4* __restrict__ qp, const uint4* __restrict__ kp,
              const uint4* __restrict__ vp,
              const float* __restrict__ cmax, const float* __restrict__ cinv,
              float* __restrict__ part) {
    __shared__ unsigned short Ph[2][128 * 72];
    const int tid  = threadIdx.x;
    const int lane = tid & 63;
    const int w    = tid >> 6;        // 0..7
    const int wm   = w & 3;           // m-subtile (32 rows)
    const int wd   = w >> 2;          // n-half (A) / d-half (B)
    const int lane31 = lane & 31;
    const int kh8    = (lane >> 5) * 8;

    const int bid  = blockIdx.x;
    const int low3 = bid & 7;
    const int rest = bid >> 3;
    const int ghi  = rest & 3;
    const int mt   = rest >> 2;       // 0..15
    const int g    = ghi * 8 + low3;  // 0..31
    const int b    = g >> 4;
    const int ns   = g & 15;
    const int m0   = mt * 128;

    // q tile -> registers, once (coalesced 1 KB per packet)
    uint4 qf[16];
    {
        const size_t qb = ((size_t)(((b * M_ + m0) >> 5) + wm) * 16) * 64 + lane;
        #pragma unroll
        for (int ks = 0; ks < 16; ++ks) qf[ks] = qp[qb + ks * 64];
    }

    f32x16 oacc[4];
    #pragma unroll
    for (int t = 0; t < 4; ++t) oacc[t] = (f32x16)0.0f;

    for (int c = 0; c < NPB_ / 64; ++c) {
        const int nbase = ns * NPB_ + c * 64;
        unsigned short* Pb = Ph[c & 1];
        // ---- phase A: S quadrant (rows wm*32, n-cols wd*32) ----
        const size_t kb = ((size_t)(((b * N_ + nbase) >> 5) + wd) * 16) * 64 + lane;
        f32x16 s = (f32x16)0.0f;
        #pragma unroll
        for (int ks = 0; ks < 16; ++ks)
            MFMA16(s, as_h8(qf[ks]), as_h8(kp[kb + ks * 64]));
        const int nc = nbase + wd * 32 + lane31;
        const float cmv = cmax[b * N_ + nc];
        const float civ = cinv[b * N_ + nc];
        #pragma unroll
        for (int r = 0; r < 16; ++r) {
            const int row = wm * 32 + cd_row(r, lane);
            Pb[row * 72 + wd * 32 + lane31] = f16bits(__expf(s[r] * SCALE_ - cmv) * civ);
        }
        __syncthreads();
        // ---- phase B: oacc(32 m x 128 d) += P @ V ----
        const unsigned short* prh = Pb + (wm * 32 + lane31) * 72 + kh8;
        const size_t gg0 = (size_t)((b * N_ + nbase) >> 4);
        #pragma unroll
        for (int k2 = 0; k2 < 4; ++k2) {
            const f16x8 a2 = as_h8(*reinterpret_cast<const uint4*>(prh + k2 * 16));
            #pragma unroll
            for (int dt = 0; dt < 4; ++dt) {
                MFMA16(oacc[dt], a2, as_h8(vp[((gg0 + k2) * 8 + wd * 4 + dt) * 64 + lane]));
            }
        }
        // no trailing barrier: next chunk writes the other Ph buffer
    }
    float* pb = part + (size_t)low3 * OUTSZ_;
    #pragma unroll
    for (int dt = 0; dt < 4; ++dt) {
        #pragma unroll
        for (int r = 0; r < 16; ++r) {
            const int row  = m0 + wm * 32 + cd_row(r, lane);
            atomicAdd(&pb[((size_t)(b * M_ + row)) * D_ + wd * 128 + dt * 32 + lane31],
                      oacc[dt][r]);
        }
    }
}

// ---------------- K5: out = v_features + sum(parts) ----------------
__global__ void reduce_out(const float4* __restrict__ v, const float4* __restrict__ part,
                           float4* __restrict__ out) {
    const size_t i = (size_t)blockIdx.x * 256 + threadIdx.x;
    float4 a = v[i];
    #pragma unroll
    for (int c = 0; c < NCOPY_; ++c) {
        const float4 p = part[(size_t)c * (OUTSZ_ / 4) + i];
        a.x += p.x; a.y += p.y; a.z += p.z; a.w += p.w;
    }
    out[i] = a;
}

} // anonymous namespace

extern "C" void kernel_launch(void* const* d_in, const int* in_sizes, int n_in,
                              void* d_out, int out_size, void* d_ws, size_t ws_size,
                              hipStream_t stream) {
    const float* p_xyz      = (const float*)d_in[0];
    const float* v_xyz      = (const float*)d_in[1];
    const float* p_features = (const float*)d_in[2];
    const float* v_features = (const float*)d_in[3];
    const float* Wq  = (const float*)d_in[4];
    const float* bq  = (const float*)d_in[5];
    const float* Wk  = (const float*)d_in[6];
    const float* bk  = (const float*)d_in[7];
    const float* Wv  = (const float*)d_in[8];
    const float* bv  = (const float*)d_in[9];
    const float* Wp1 = (const float*)d_in[10];
    const float* bp1 = (const float*)d_in[11];
    const float* lnw = (const float*)d_in[12];
    const float* lnb = (const float*)d_in[13];
    const float* Wp2 = (const float*)d_in[14];
    const float* bp2 = (const float*)d_in[15];
    float* out = (float*)d_out;

    // ---- workspace carve-up (256B aligned), ~70 MB ----
    char* p = (char*)d_ws;
    auto alloc = [&](size_t bytes) {
        void* r = (void*)p;
        p += (bytes + 255) & ~(size_t)255;
        return r;
    };
    uint4* qpk = (uint4*)alloc((size_t)B_*M_*D_*2);   // fp16 packets
    uint4* kpk = (uint4*)alloc((size_t)B_*N_*D_*2);
    uint4* vpk = (uint4*)alloc((size_t)B_*N_*D_*2);
    uint4* wp  = (uint4*)alloc((size_t)3*D_*D_*2);
    float4* hr4 = (float4*)alloc((size_t)B_*N_*16);
    float*  cm  = (float*)alloc((size_t)B_*N_*4);
    float*  ci  = (float*)alloc((size_t)B_*N_*4);
    float*  part = (float*)alloc((size_t)NCOPY_*OUTSZ_*4);   // 33.5 MB

    constexpr size_t WMAT = (size_t)D_*D_/8;   // uint4 per weight matrix

    prep_wt<<<3*8, 256, 0, stream>>>(Wq, Wk, Wv, wp);
    prep_hr<<<(B_*N_)/256, 256, 0, stream>>>(p_xyz, v_xyz, Wp1, bp1, lnw, lnb, hr4);
    hipMemsetAsync(part, 0, (size_t)NCOPY_*OUTSZ_*4, stream);

    gemm_qkv<0><<<(B_*M_)/64, 256, 0, stream>>>(v_features, wp + 0*WMAT, bq, hr4, Wp2, bp2, qpk);
    gemm_qkv<1><<<(B_*N_)/64, 256, 0, stream>>>(p_features, wp + 1*WMAT, bk, hr4, Wp2, bp2, kpk);
    gemm_qkv<2><<<(B_*N_)/64, 256, 0, stream>>>(p_features, wp + 2*WMAT, bv, hr4, Wp2, bp2, vpk);

    col_stats<<<512, 256, 0, stream>>>(qpk, kpk, cm, ci);
    attn_out<<<B_*NS_*(M_/128), 512, 0, stream>>>(qpk, kpk, vpk, cm, ci, part);
    reduce_out<<<(OUTSZ_/4)/256, 256, 0, stream>>>((const float4*)v_features,
                                                   (const float4*)part, (float4*)out);
}